// Round 5
// baseline (6037.914 us; speedup 1.0000x reference)
//
#include <hip/hip_runtime.h>

// fp32 I/O. N=32, C=64, T=256, V=50, H=8, hc=8
// plane = T*V = 12800, n-stride = 819200, score K-dim = hc*T = 2048.
// n processed in 4 groups of 8; k tensor staged in d_out (same fp32 size),
// overwritten by K3(g) only after K2(g) consumed it (stream order).
// v-projection folded into o-projection: W2T[s,a,o] = sum_c ow[o,s*64+c]*vw[c,a],
// ovb[s,o] = sum_c ow[o,s*64+c]*vb[c]  ->  K3 reads x_kv directly, no v tensor.
//
// R5 change (post-mortem of R4: 229us @ VALUBusy 54%, occupancy 21% = 2
// waves/SIMD; LDS:VALU = 0.5 B/FLOP is exactly the CU balance point, so both
// pipes need deep cross-wave overlap -> occupancy is the lever):
//   - K3 sp shrunk 4x: P-write + GEMM2-consume split into 4 rm-pair passes
//     per s (pure reordering: same LDS/global/FMA totals). sp = 16 slots/wave
//     (4KB). LDS 77,824 -> 43,008 B => 3 blocks/CU = 3 waves/SIMD.
//   - __launch_bounds__(256,3) to pin VGPR <= 170.
//   - Swizzle: row = 2*(u>>3)+(u&1), XOR = 16*(u>>3) on both sides.

// ---------------------------------------------------------------------------
// K0: wT (q/k weight transpose, [c][o]) + W2T (pre-transposed [s][a][o]) + ovb
__global__ void k0_prep(const float* __restrict__ qw, const float* __restrict__ kw,
                        const float* __restrict__ vw, const float* __restrict__ vb,
                        const float* __restrict__ ow,
                        float* __restrict__ wT, float* __restrict__ W2T,
                        float* __restrict__ ovb)
{
    int i = threadIdx.x + blockIdx.x * 256;
    if (i < 4096){
        int o = i >> 6, c = i & 63;
        wT[c*64 + o]        = qw[i];
        wT[4096 + c*64 + o] = kw[i];
    } else if (i < 36864){
        int j = i - 4096;
        int s = j >> 12, o = (j >> 6) & 63, a = j & 63;
        float acc = 0.f;
        for (int c = 0; c < 64; ++c)
            acc += ow[o*512 + s*64 + c] * vw[c*64 + a];
        W2T[s*4096 + a*64 + o] = acc;            // transposed store
    } else if (i < 37376){
        int j = i - 36864;
        int s = j >> 6, o = j & 63;
        float acc = 0.f;
        for (int c = 0; c < 64; ++c)
            acc += ow[o*512 + s*64 + c] * vb[c];
        ovb[j] = acc;
    }
}

// ---------------------------------------------------------------------------
// K1: q,k projections for one n-group. Block = (pos-tile, n_rel).
// q -> qchunk (group-relative), k -> d_out (absolute).
__global__ __launch_bounds__(256, 2) void k1_qk(
    const float* __restrict__ xq, const float* __restrict__ xkv,
    const float* __restrict__ wT,
    const float* __restrict__ qb, const float* __restrict__ kb,
    float* __restrict__ qo, float* __restrict__ ko, int n0)
{
    __shared__ float sx[64*256];              // 64 KB, one tensor at a time
    const int nrel = blockIdx.y;
    const int nabs = n0 + nrel;
    const int p0   = blockIdx.x * 256;
    const int tid  = threadIdx.x;
    const size_t abase = (size_t)nabs * 819200;
    const size_t rbase = (size_t)nrel * 819200;

    for (int phase = 0; phase < 2; ++phase){
        const float* src  = phase ? xkv : xq;
        const float* bias = phase ? kb : qb;
        const float* w    = phase ? (wT + 4096) : wT;

        if (phase) __syncthreads();           // readers of prev sx done
        {   // stage 64x256 fp32 tile, float4 coalesced
            const float* g = src + abase + p0;
            #pragma unroll
            for (int j = 0; j < 16; ++j){
                int i4 = tid + j*256;         // 0..4095 float4s
                int c = i4 >> 6, m4 = i4 & 63;
                float4 val = *(const float4*)(g + (size_t)c*12800 + m4*4);
                *(float4*)(&sx[c*256 + m4*4]) = val;
            }
        }
        __syncthreads();

        for (int h = 0; h < 2; ++h){
            const int o0 = h*32;
            float acc[32];
            #pragma unroll
            for (int j = 0; j < 32; ++j) acc[j] = bias[o0+j];
            for (int c = 0; c < 64; ++c){
                float xv = sx[c*256 + tid];
                const float* row = w + c*64 + o0;
                #pragma unroll
                for (int j = 0; j < 32; ++j) acc[j] += row[j] * xv;
            }
            float* dst = phase ? (ko + abase) : (qo + rbase);
            #pragma unroll
            for (int j = 0; j < 32; ++j)
                dst[(size_t)(o0+j)*12800 + p0 + tid] = acc[j];
        }
    }
}

// ---------------------------------------------------------------------------
// K2p: partial scores. Block = n_rel*32 + s*4 + kq (256 blocks/group).
// Each wave sums 128 K-rows; q per-lane, k rows wave-uniform (scalar loads).
__global__ __launch_bounds__(256, 2) void k2_partial(
    const float* __restrict__ qc, const float* __restrict__ kd,
    float* __restrict__ pscore, int n0)
{
    __shared__ float red[4*2500];             // 40 KB
    const int bid  = blockIdx.x;
    const int kq   = bid & 3;
    const int s    = (bid >> 2) & 7;
    const int nrel = bid >> 5;
    const int tid  = threadIdx.x;
    const int wave = __builtin_amdgcn_readfirstlane(tid >> 6);
    const int lane = tid & 63;
    const float* qf = qc + (size_t)nrel * 819200 + (size_t)s * 102400;
    const float* kf = kd + (size_t)(n0 + nrel) * 819200 + (size_t)s * 102400;

    float acc[50];
    #pragma unroll
    for (int w = 0; w < 50; ++w) acc[w] = 0.f;

    if (lane < 50){
        const int r0 = kq*512 + wave*128;
        for (int kk = r0; kk < r0 + 128; kk += 4){
            float qv[4];
            #pragma unroll
            for (int t = 0; t < 4; ++t) qv[t] = qf[(size_t)(kk+t)*50 + lane];
            #pragma unroll
            for (int t = 0; t < 4; ++t){
                const float* kr = kf + (size_t)(kk+t)*50;   // wave-uniform
                #pragma unroll
                for (int w = 0; w < 50; ++w) acc[w] += qv[t] * kr[w];
            }
        }
        #pragma unroll
        for (int w = 0; w < 50; ++w) red[wave*2500 + lane*50 + w] = acc[w];
    }
    __syncthreads();

    for (int i = tid; i < 2500; i += 256)
        pscore[(size_t)bid*2500 + i] = red[i] + red[2500+i] + red[5000+i] + red[7500+i];
}

// ---------------------------------------------------------------------------
// K2f: attn = tanh(score/2048)*alpha + gattn. Block = n_rel*8 + s.
// Output rows padded to stride 52 (attnc[b][u][52], cols 50..51 unwritten)
// so K3's global float4 reads stay 16B-aligned.
__global__ void k2_final(const float* __restrict__ pscore,
                         const float* __restrict__ alphas, const float* __restrict__ gattn,
                         float* __restrict__ attnc)
{
    const int b = blockIdx.x;
    const int s = b & 7;
    const float inv = 1.0f / 2048.0f;
    const float alpha = alphas[s];
    for (int i = threadIdx.x; i < 2500; i += 256){
        float sum = pscore[(size_t)(b*4+0)*2500 + i] + pscore[(size_t)(b*4+1)*2500 + i]
                  + pscore[(size_t)(b*4+2)*2500 + i] + pscore[(size_t)(b*4+3)*2500 + i];
        int u = i / 50, w = i - u*50;
        attnc[(size_t)b*2600 + u*52 + w] = tanhf(sum * inv) * alpha + gattn[i];
    }
}

// ---------------------------------------------------------------------------
// K3 v5: two chained register-tiled GEMMs, s-split across wave pairs,
// P staged in rm-pair passes (sp = 16 slots/wave -> 3 blocks/CU).
// Block = (tb, nrel): trows tb*2 + {0,1}. 256 thr = 4 waves.
// Wave wv: tloc = wv&1 (trow), sh = wv>>1 (s-half: s in [4*sh, 4*sh+4)).
// Lane: WL = lane>>3 (o-group), WS = lane&7 (u/w-group); per-lane 8x8 tile.
//   GEMM1: P[o,u] = ovb + W2T_s[a,o].x[a,trow,u]  (W2T, ovb from GLOBAL/L1)
//   pass h=0..3: write P cols u&7 in {2h,2h+1}; GEMM2 over those u
//     slot = 2*(u>>3) + (u&1); swizzle byte ^= 16*(u>>3) both sides.
// LDS (dynamic, 43,008 B -> 3 blocks/CU = 3 waves/SIMD):
//   sx [2][64][52] x tile; sp [4][16][64] per-wave P slots
//   red (epilogue overlay at lds+0): [128][68] cross-pair acc2 reduction
__global__ __launch_bounds__(256, 3) void k3_out(
    const float* __restrict__ xkv, const float* __restrict__ attnc,
    const float* __restrict__ W2T, const float* __restrict__ ovb,
    const float* __restrict__ ob, float* __restrict__ out, int n0)
{
    extern __shared__ float lds[];
    float* sx = lds;                 // 6656 floats (2*64*52)
    float* sp = lds + 6656;          // 4096 floats (4 waves * 16 slots * 64)

    const int nrel = blockIdx.y;
    const int tb   = blockIdx.x;
    const int tid  = threadIdx.x;
    const int wv   = __builtin_amdgcn_readfirstlane(tid >> 6);
    const int lane = tid & 63;
    const int tloc = wv & 1;
    const int sh   = wv >> 1;
    const int WL   = lane >> 3;
    const int WS   = lane & 7;
    const int trow = tb*2 + tloc;
    const size_t abase = (size_t)(n0 + nrel) * 819200;

    // ---- stage x tile: sx[tt][a][u] (stride 52), 2 trows x 64 a x 50 u ----
    {
        const float4* xg = (const float4*)(xkv + abase);
        for (int i4 = tid; i4 < 1600; i4 += 256){
            int a = i4 / 25, j = i4 - a*25;          // 25 f4 = 100 floats per a
            float4 v = xg[(size_t)a*3200 + tb*25 + j];
            int g0 = j*4;
            #pragma unroll
            for (int e = 0; e < 4; ++e){
                int g = g0 + e;                      // 0..99 = (tt, u)
                int tt = (g >= 50) ? 1 : 0;
                sx[tt*3328 + a*52 + (g - tt*50)] = ((const float*)&v)[e];
            }
        }
    }
    __syncthreads();

    float acc2[8][8];
    #pragma unroll
    for (int ro = 0; ro < 8; ++ro)
        #pragma unroll
        for (int rw = 0; rw < 8; ++rw) acc2[ro][rw] = 0.f;

    const float* xw  = sx + tloc*3328 + 8*WS;     // + a*52 (LDS)
    char*        pb8 = (char*)(sp + wv*1024);     // wave-private P (4 KB)
    const float* agb = attnc + (size_t)(nrel*8)*2600 + 8*WS;   // + s*2600 + u*52

    for (int si = 0; si < 4; ++si){
        const int s = sh*4 + si;

        // ---- GEMM1: P[o,u] = ovb[s,o] + sum_a W2T_s[a,o] * x[a,trow,u] ----
        float acc1[8][8];
        {
            float pbv[8];
            *(float4*)&pbv[0] = *(const float4*)(ovb + s*64 + 8*WL);
            *(float4*)&pbv[4] = *(const float4*)(ovb + s*64 + 8*WL + 4);
            #pragma unroll
            for (int ro = 0; ro < 8; ++ro)
                #pragma unroll
                for (int rm = 0; rm < 8; ++rm) acc1[ro][rm] = pbv[ro];
        }
        const float* wS = W2T + s*4096 + 8*WL;    // global, L1-resident slice
        #pragma unroll 2
        for (int a = 0; a < 64; ++a){
            float wvx[8], xv[8];
            *(float4*)&wvx[0] = *(const float4*)(wS + a*64);      // global f4
            *(float4*)&wvx[4] = *(const float4*)(wS + a*64 + 4);  // global f4
            *(float4*)&xv[0]  = *(const float4*)(xw + a*52);      // LDS b128
            *(float4*)&xv[4]  = *(const float4*)(xw + a*52 + 4);  // LDS b128
            #pragma unroll
            for (int ro = 0; ro < 8; ++ro)
                #pragma unroll
                for (int rm = 0; rm < 8; ++rm)
                    acc1[ro][rm] = fmaf(wvx[ro], xv[rm], acc1[ro][rm]);
        }

        // ---- 4 rm-pair passes: write P slots, then GEMM2 over those u ----
        const float* aS = agb + (size_t)s*2600;
        #pragma unroll
        for (int h = 0; h < 4; ++h){
            // write: u = 8*WS + 2h+d, slot row = 2*WS + d, xor = 16*WS
            #pragma unroll
            for (int d = 0; d < 2; ++d){
                const int rm = 2*h + d;
                const int u  = 8*WS + rm;
                if (u < 50){
                    char* row = pb8 + (2*WS + d)*256;
                    const int xo = 16*WS;
                    *(float4*)(row + ((32*WL +  0) ^ xo)) =
                        make_float4(acc1[0][rm], acc1[1][rm], acc1[2][rm], acc1[3][rm]);
                    *(float4*)(row + ((32*WL + 16) ^ xo)) =
                        make_float4(acc1[4][rm], acc1[5][rm], acc1[6][rm], acc1[7][rm]);
                }
            }
            // consume: u = 8j + 2h+d (u<50 compile-time), slot 2j+d, xor 16*j
            #pragma unroll
            for (int j = 0; j < 7; ++j){
                #pragma unroll
                for (int d = 0; d < 2; ++d){
                    const int u = 8*j + 2*h + d;
                    if (u < 50){
                        const int xo = 16*j;
                        const char* prow = pb8 + (2*j + d)*256;
                        float pv[8], av[8];
                        *(float4*)&pv[0] = *(const float4*)(prow + ((32*WL +  0) ^ xo));
                        *(float4*)&pv[4] = *(const float4*)(prow + ((32*WL + 16) ^ xo));
                        *(float4*)&av[0] = *(const float4*)(aS + u*52);       // global f4
                        *(float4*)&av[4] = *(const float4*)(aS + u*52 + 4);   // global f4
                        #pragma unroll
                        for (int ro = 0; ro < 8; ++ro)
                            #pragma unroll
                            for (int rw = 0; rw < 8; ++rw)
                                acc2[ro][rw] = fmaf(pv[ro], av[rw], acc2[ro][rw]);
                    }
                }
            }
        }
    }

    // ---- cross-pair (s-half) reduction through LDS overlay, then store ----
    __syncthreads();                              // sx/sp dead now
    float* red = lds;                             // [128][68] floats
    if (sh == 1){
        float* r = red + (tloc*64 + lane)*68;
        #pragma unroll
        for (int j = 0; j < 16; ++j){
            const int ro = (4*j) >> 3, rw = (4*j) & 7;
            *(float4*)(r + 4*j) = make_float4(acc2[ro][rw],   acc2[ro][rw+1],
                                              acc2[ro][rw+2], acc2[ro][rw+3]);
        }
    }
    __syncthreads();
    if (sh == 0){
        const float* r = red + (tloc*64 + lane)*68;
        #pragma unroll
        for (int j = 0; j < 16; ++j){
            const int ro = (4*j) >> 3, rw = (4*j) & 7;
            float4 rv = *(const float4*)(r + 4*j);
            acc2[ro][rw]   += rv.x;  acc2[ro][rw+1] += rv.y;
            acc2[ro][rw+2] += rv.z;  acc2[ro][rw+3] += rv.w;
        }
        #pragma unroll
        for (int ro = 0; ro < 8; ++ro){
            const int o = 8*WL + ro;
            const float b = ob[o];
            float* op = out + abase + (size_t)o*12800 + trow*50;
            #pragma unroll
            for (int j = 0; j < 4; ++j){
                const int w0 = 8*WS + 2*j;
                if (w0 <= 48)
                    *(float2*)(op + w0) = make_float2(acc2[ro][2*j]   + b,
                                                      acc2[ro][2*j+1] + b);
            }
        }
    }
}

// ---------------------------------------------------------------------------
extern "C" void kernel_launch(void* const* d_in, const int* in_sizes, int n_in,
                              void* d_out, int out_size, void* d_ws, size_t ws_size,
                              hipStream_t stream)
{
    const float* x_q    = (const float*)d_in[0];
    const float* x_kv   = (const float*)d_in[1];
    const float* q_w    = (const float*)d_in[2];
    const float* q_b    = (const float*)d_in[3];
    const float* k_w    = (const float*)d_in[4];
    const float* k_b    = (const float*)d_in[5];
    const float* v_w    = (const float*)d_in[6];
    const float* v_b    = (const float*)d_in[7];
    const float* o_w    = (const float*)d_in[8];
    const float* o_b    = (const float*)d_in[9];
    const float* alphas = (const float*)d_in[10];
    const float* gattn  = (const float*)d_in[11];
    float* out = (float*)d_out;

    // ws layout (29.6 MB):
    char* ws = (char*)d_ws;
    float* qchunk = (float*)(ws);                  // 26,214,400 B (8n q fp32)
    float* pscore = (float*)(ws + 26214400);       //  2,560,000 B
    float* attnc  = (float*)(ws + 28774400);       //    665,600 B (stride-52 rows)
    float* wT     = (float*)(ws + 29440000);       //     32,768 B
    float* W2T    = (float*)(ws + 29472768);       //    131,072 B
    float* ovb    = (float*)(ws + 29603840);       //      2,048 B

    // idempotent, host-side only (legal under graph capture); no static state
    hipFuncSetAttribute((const void*)k3_out,
                        hipFuncAttributeMaxDynamicSharedMemorySize, 43008);

    k0_prep<<<146, 256, 0, stream>>>(q_w, k_w, v_w, v_b, o_w, wT, W2T, ovb);

    for (int g = 0; g < 4; ++g){
        const int n0 = g * 8;
        k1_qk<<<dim3(50, 8), 256, 0, stream>>>(x_q, x_kv, wT, q_b, k_b,
                                               qchunk, out /*k in d_out*/, n0);
        k2_partial<<<256, 256, 0, stream>>>(qchunk, (const float*)d_out, pscore, n0);
        k2_final<<<64, 256, 0, stream>>>(pscore, alphas, gattn, attnc);
        k3_out<<<dim3(128, 8), 256, 43008, stream>>>(x_kv, attnc, W2T, ovb, o_b, out, n0);
    }
}